// Round 1
// baseline (1077.804 us; speedup 1.0000x reference)
//
#include <hip/hip_runtime.h>
#include <stdint.h>
#include <stddef.h>

#define SLEN 2048
#define BATCH 2
#define NHEAD 16
#define HDIM 64
#define HID 1024

typedef __attribute__((ext_vector_type(8))) short s16x8;
typedef __attribute__((ext_vector_type(4))) float f32x4;

#define MFMA(a, b, c) __builtin_amdgcn_mfma_f32_16x16x32_bf16((a), (b), (c), 0, 0, 0)

static __device__ __forceinline__ unsigned short f2bf(float f) {
  unsigned u = __builtin_bit_cast(unsigned, f);
  u += 0x7fffu + ((u >> 16) & 1u);   // RNE
  return (unsigned short)(u >> 16);
}

static __device__ __forceinline__ void gload_lds16(const void* g, void* l) {
  __builtin_amdgcn_global_load_lds((__attribute__((address_space(1))) void*)g,
                                   (__attribute__((address_space(3))) void*)l, 16, 0, 0);
}

// ---------------- fp32 -> bf16 conversion (4 arrays per launch, same n) ----------
__global__ __launch_bounds__(256) void cvt_kernel(
    const float* __restrict__ s0, const float* __restrict__ s1,
    const float* __restrict__ s2, const float* __restrict__ s3,
    unsigned short* __restrict__ d0, unsigned short* __restrict__ d1,
    unsigned short* __restrict__ d2, unsigned short* __restrict__ d3, int n) {
  const float* s;
  unsigned short* d;
  switch (blockIdx.y) {
    case 0: s = s0; d = d0; break;
    case 1: s = s1; d = d1; break;
    case 2: s = s2; d = d2; break;
    default: s = s3; d = d3; break;
  }
  int i = (blockIdx.x * 256 + threadIdx.x) * 4;
  if (i >= n) return;
  float4 v = *(const float4*)(s + i);
  ushort4 o;
  o.x = f2bf(v.x); o.y = f2bf(v.y); o.z = f2bf(v.z); o.w = f2bf(v.w);
  *(ushort4*)(d + i) = o;
}

// ---------------- mask -> bitmask: bits[b][q][w] bit j = (mask[b][q][w*32+j]!=0) ----
__global__ __launch_bounds__(256) void maskbits_kernel(const int* __restrict__ mask,
                                                       unsigned* __restrict__ bits) {
  int i = blockIdx.x * 256 + threadIdx.x;  // word id over BATCH*SLEN*64
  const int* mp = mask + (size_t)i * 32;
  unsigned wv = 0;
#pragma unroll
  for (int j = 0; j < 8; ++j) {
    int4 m4 = *(const int4*)(mp + j * 4);
    wv |= (m4.x ? 1u : 0u) << (j * 4 + 0);
    wv |= (m4.y ? 1u : 0u) << (j * 4 + 1);
    wv |= (m4.z ? 1u : 0u) << (j * 4 + 2);
    wv |= (m4.w ? 1u : 0u) << (j * 4 + 3);
  }
  bits[i] = wv;
}

// ---------------- bf16 NT GEMM: C = A[M,K] * Bt[N,K]^T + bias ----------------
// MODE 0: bf16 natural [M,N]. MODE 1: bf16 Vt[b][h][d][s]. MODE 2: fp32 natural.
template <int MODE>
__global__ __launch_bounds__(256, 2) void gemm_nt(
    const unsigned short* __restrict__ A, const unsigned short* __restrict__ Bt,
    const float* __restrict__ bias, void* __restrict__ Cout, int M, int N, int K) {
  __shared__ unsigned short lA[4096];  // [128][32]
  __shared__ unsigned short lB[4096];
  const int tid = threadIdx.x;
  const int lane = tid & 63;
  const int w = tid >> 6;
  const int wm = w >> 1, wn = w & 1;
  const int lr = lane & 15, lg = lane >> 4;

  const char* Ab = (const char*)A + ((size_t)blockIdx.x * 128) * (size_t)(K * 2);
  const char* Bb = (const char*)Bt + ((size_t)blockIdx.y * 128) * (size_t)(K * 2);
  const int cid0 = w * 2, cid1 = w * 2 + 1;
  const int o0 = cid0 * 1024 + lane * 16, o1 = cid1 * 1024 + lane * 16;
  const char* aSrc0 = Ab + (size_t)(o0 >> 6) * (K * 2) + (o0 & 63);
  const char* aSrc1 = Ab + (size_t)(o1 >> 6) * (K * 2) + (o1 & 63);
  const char* bSrc0 = Bb + (size_t)(o0 >> 6) * (K * 2) + (o0 & 63);
  const char* bSrc1 = Bb + (size_t)(o1 >> 6) * (K * 2) + (o1 & 63);

  f32x4 acc[4][4];
  const f32x4 z = {0.f, 0.f, 0.f, 0.f};
#pragma unroll
  for (int mi = 0; mi < 4; ++mi)
#pragma unroll
    for (int ni = 0; ni < 4; ++ni) acc[mi][ni] = z;

  for (int kt = 0; kt < K; kt += 32) {
    __syncthreads();
    gload_lds16(aSrc0 + kt * 2, &lA[cid0 * 512]);
    gload_lds16(aSrc1 + kt * 2, &lA[cid1 * 512]);
    gload_lds16(bSrc0 + kt * 2, &lB[cid0 * 512]);
    gload_lds16(bSrc1 + kt * 2, &lB[cid1 * 512]);
    __syncthreads();
    s16x8 af[4], bfr[4];
#pragma unroll
    for (int mi = 0; mi < 4; ++mi)
      af[mi] = *(const s16x8*)(&lA[(wm * 64 + mi * 16 + lr) * 32 + lg * 8]);
#pragma unroll
    for (int ni = 0; ni < 4; ++ni)
      bfr[ni] = *(const s16x8*)(&lB[(wn * 64 + ni * 16 + lr) * 32 + lg * 8]);
#pragma unroll
    for (int mi = 0; mi < 4; ++mi)
#pragma unroll
      for (int ni = 0; ni < 4; ++ni) acc[mi][ni] = MFMA(af[mi], bfr[ni], acc[mi][ni]);
  }

#pragma unroll
  for (int mi = 0; mi < 4; ++mi) {
    const int row0 = blockIdx.x * 128 + wm * 64 + mi * 16 + lg * 4;
#pragma unroll
    for (int ni = 0; ni < 4; ++ni) {
      const int col = blockIdx.y * 128 + wn * 64 + ni * 16 + lr;
      const float bv = bias[col];
#pragma unroll
      for (int r = 0; r < 4; ++r) {
        const int row = row0 + r;
        const float val = acc[mi][ni][r] + bv;
        if (MODE == 0) {
          ((unsigned short*)Cout)[(size_t)row * N + col] = f2bf(val);
        } else if (MODE == 1) {
          const int bb = row >> 11, ss = row & 2047;
          const int hh = col >> 6, dd = col & 63;
          ((unsigned short*)Cout)[(((size_t)((bb * NHEAD + hh) * HDIM + dd)) << 11) + ss] =
              f2bf(val);
        } else {
          ((float*)Cout)[(size_t)row * N + col] = val;
        }
      }
    }
  }
}

// ---------------- fused attention ----------------
// grid (S/128, B*NHEAD), 256 threads. Wave w owns 32 q-rows.
// pass1: online (max,sum) per row; pass2: recompute QK^T, write P (fp32) + PV.
__global__ __launch_bounds__(256) void attn_kernel(
    const unsigned short* __restrict__ Qp,  // [B*S, HID] bf16
    const unsigned short* __restrict__ Kp,  // [B*S, HID] bf16
    const unsigned short* __restrict__ Vt,  // [B*NHEAD*HDIM, S] bf16
    const unsigned* __restrict__ Mw,        // [B, S, 64] bitmask
    unsigned short* __restrict__ AV,        // [B*S, HID] bf16
    float* __restrict__ Pout) {             // [B*NHEAD*S, S] fp32
  __shared__ unsigned short P_lds[4][32][40];  // 80B row stride: 16B-aligned, ~2-way banks
  const int tid = threadIdx.x;
  const int lane = tid & 63;
  const int w = tid >> 6;
  const int lr = lane & 15;
  const int lg = lane >> 4;
  const int bh = blockIdx.y;
  const int b = bh >> 4;
  const int h = bh & 15;
  const int q0 = blockIdx.x * 128 + w * 32;

  const unsigned short* Qb = Qp + (size_t)(b * SLEN) * HID + h * HDIM;
  const unsigned short* Kb = Kp + (size_t)(b * SLEN) * HID + h * HDIM;
  const unsigned short* Vb = Vt + (size_t)bh * HDIM * SLEN;
  const unsigned* Mb = Mw + (size_t)(b * SLEN) * 64;
  float* Pb = Pout + (size_t)bh * SLEN * SLEN;

  s16x8 qf[2][2];
#pragma unroll
  for (int mi = 0; mi < 2; ++mi)
#pragma unroll
    for (int kb = 0; kb < 2; ++kb)
      qf[mi][kb] = *(const s16x8*)(Qb + (size_t)(q0 + mi * 16 + lr) * HID + kb * 32 + lg * 8);

  float rmax[8], rsum[8];
#pragma unroll
  for (int s = 0; s < 8; ++s) { rmax[s] = -__builtin_inff(); rsum[s] = 0.f; }

  // ---- pass 1 ----
  for (int c0 = 0; c0 < SLEN; c0 += 32) {
    unsigned mw[8];
#pragma unroll
    for (int s = 0; s < 8; ++s)
      mw[s] = Mb[(size_t)(q0 + (s >> 2) * 16 + lg * 4 + (s & 3)) * 64 + (c0 >> 5)];
#pragma unroll
    for (int cg = 0; cg < 2; ++cg) {
      const int cc = c0 + cg * 16;
      const s16x8 kf0 = *(const s16x8*)(Kb + (size_t)(cc + lr) * HID + lg * 8);
      const s16x8 kf1 = *(const s16x8*)(Kb + (size_t)(cc + lr) * HID + 32 + lg * 8);
      f32x4 acc[2];
      acc[0] = (f32x4){0.f, 0.f, 0.f, 0.f};
      acc[1] = (f32x4){0.f, 0.f, 0.f, 0.f};
      acc[0] = MFMA(qf[0][0], kf0, acc[0]);
      acc[0] = MFMA(qf[0][1], kf1, acc[0]);
      acc[1] = MFMA(qf[1][0], kf0, acc[1]);
      acc[1] = MFMA(qf[1][1], kf1, acc[1]);
      const int cbit = cg * 16 + lr;
#pragma unroll
      for (int s = 0; s < 8; ++s) {
        float e = acc[s >> 2][s & 3] * 0.125f;
        e = ((mw[s] >> cbit) & 1u) ? e : -1e10f;
        const float m = rmax[s];
        if (e > m) {
          rsum[s] = rsum[s] * __expf(m - e) + 1.f;
          rmax[s] = e;
        } else {
          rsum[s] += __expf(e - m);
        }
      }
    }
  }
  // merge (max,sum) across the 16 lanes of each row group
#pragma unroll
  for (int s = 0; s < 8; ++s) {
    float m = rmax[s], l = rsum[s];
#pragma unroll
    for (int d = 1; d < 16; d <<= 1) {
      const float mo = __shfl_xor(m, d);
      const float lo = __shfl_xor(l, d);
      const float M = fmaxf(m, mo);
      l = l * __expf(m - M) + lo * __expf(mo - M);
      m = M;
    }
    rmax[s] = m;
    rsum[s] = 1.f / l;  // now holds 1/denominator
  }

  // ---- pass 2: recompute, write P, accumulate PV ----
  f32x4 oacc[2][4];
  const f32x4 z = {0.f, 0.f, 0.f, 0.f};
#pragma unroll
  for (int mi = 0; mi < 2; ++mi)
#pragma unroll
    for (int nd = 0; nd < 4; ++nd) oacc[mi][nd] = z;

  for (int c0 = 0; c0 < SLEN; c0 += 32) {
    unsigned mw[8];
#pragma unroll
    for (int s = 0; s < 8; ++s)
      mw[s] = Mb[(size_t)(q0 + (s >> 2) * 16 + lg * 4 + (s & 3)) * 64 + (c0 >> 5)];
#pragma unroll
    for (int cg = 0; cg < 2; ++cg) {
      const int cc = c0 + cg * 16;
      const s16x8 kf0 = *(const s16x8*)(Kb + (size_t)(cc + lr) * HID + lg * 8);
      const s16x8 kf1 = *(const s16x8*)(Kb + (size_t)(cc + lr) * HID + 32 + lg * 8);
      f32x4 acc[2];
      acc[0] = (f32x4){0.f, 0.f, 0.f, 0.f};
      acc[1] = (f32x4){0.f, 0.f, 0.f, 0.f};
      acc[0] = MFMA(qf[0][0], kf0, acc[0]);
      acc[0] = MFMA(qf[0][1], kf1, acc[0]);
      acc[1] = MFMA(qf[1][0], kf0, acc[1]);
      acc[1] = MFMA(qf[1][1], kf1, acc[1]);
      const int cbit = cg * 16 + lr;
      const int col = cc + lr;
#pragma unroll
      for (int s = 0; s < 8; ++s) {
        const int lrow = (s >> 2) * 16 + lg * 4 + (s & 3);
        float e = acc[s >> 2][s & 3] * 0.125f;
        e = ((mw[s] >> cbit) & 1u) ? e : -1e10f;
        const float p = __expf(e - rmax[s]) * rsum[s];
        Pb[(size_t)(q0 + lrow) * SLEN + col] = p;
        P_lds[w][lrow][cg * 16 + lr] = f2bf(p);
      }
    }
    const s16x8 pf0 = *(const s16x8*)(&P_lds[w][lr][lg * 8]);
    const s16x8 pf1 = *(const s16x8*)(&P_lds[w][16 + lr][lg * 8]);
#pragma unroll
    for (int nd = 0; nd < 4; ++nd) {
      const s16x8 vf = *(const s16x8*)(Vb + (size_t)(nd * 16 + lr) * SLEN + c0 + lg * 8);
      oacc[0][nd] = MFMA(pf0, vf, oacc[0][nd]);
      oacc[1][nd] = MFMA(pf1, vf, oacc[1][nd]);
    }
  }

#pragma unroll
  for (int mi = 0; mi < 2; ++mi)
#pragma unroll
    for (int nd = 0; nd < 4; ++nd)
#pragma unroll
      for (int r = 0; r < 4; ++r) {
        const int qrow = q0 + mi * 16 + lg * 4 + r;
        const int d = nd * 16 + lr;
        AV[(size_t)(b * SLEN + qrow) * HID + h * HDIM + d] = f2bf(oacc[mi][nd][r]);
      }
}

extern "C" void kernel_launch(void* const* d_in, const int* in_sizes, int n_in,
                              void* d_out, int out_size, void* d_ws, size_t ws_size,
                              hipStream_t stream) {
  const float* q = (const float*)d_in[0];
  const float* k = (const float*)d_in[1];
  const float* v = (const float*)d_in[2];
  const int* mask = (const int*)d_in[3];
  const float* Wq = (const float*)d_in[4];
  const float* bq = (const float*)d_in[5];
  const float* Wk = (const float*)d_in[6];
  const float* bk = (const float*)d_in[7];
  const float* Wv = (const float*)d_in[8];
  const float* bv = (const float*)d_in[9];
  const float* Wo = (const float*)d_in[10];
  const float* bo = (const float*)d_in[11];

  unsigned short* qb = (unsigned short*)d_ws;
  unsigned short* kb = qb + 4194304;
  unsigned short* vb = kb + 4194304;
  unsigned short* Wqb = vb + 4194304;
  unsigned short* Wkb = Wqb + 1048576;
  unsigned short* Wvb = Wkb + 1048576;
  unsigned short* Wob = Wvb + 1048576;
  unsigned short* Qp = Wob + 1048576;
  unsigned short* Kp = Qp + 4194304;
  unsigned short* Vt = Kp + 4194304;
  unsigned short* AVb = Vt + 4194304;
  unsigned* Mw = (unsigned*)(AVb + 4194304);  // 1 MB bitmask

  float* X = (float*)d_out;
  float* Pout = X + 4194304;

  cvt_kernel<<<dim3(4096, 3), 256, 0, stream>>>(q, k, v, q, qb, kb, vb, qb, 4194304);
  cvt_kernel<<<dim3(1024, 4), 256, 0, stream>>>(Wq, Wk, Wv, Wo, Wqb, Wkb, Wvb, Wob, 1048576);
  maskbits_kernel<<<1024, 256, 0, stream>>>(mask, Mw);
  gemm_nt<0><<<dim3(32, 8), 256, 0, stream>>>(qb, Wqb, bq, Qp, 4096, 1024, 1024);
  gemm_nt<0><<<dim3(32, 8), 256, 0, stream>>>(kb, Wkb, bk, Kp, 4096, 1024, 1024);
  gemm_nt<1><<<dim3(32, 8), 256, 0, stream>>>(vb, Wvb, bv, Vt, 4096, 1024, 1024);
  attn_kernel<<<dim3(16, 32), 256, 0, stream>>>(Qp, Kp, Vt, Mw, AVb, Pout);
  gemm_nt<2><<<dim3(32, 8), 256, 0, stream>>>(AVb, Wob, bo, X, 4096, 1024, 1024);
}

// Round 4
// 1035.361 us; speedup vs baseline: 1.0410x; 1.0410x over previous
//
#include <hip/hip_runtime.h>
#include <stdint.h>
#include <stddef.h>

#define SLEN 2048
#define BATCH 2
#define NHEAD 16
#define HDIM 64
#define HID 1024

typedef __attribute__((ext_vector_type(8))) short s16x8;
typedef __attribute__((ext_vector_type(4))) float f32x4;

#define MFMA(a, b, c) __builtin_amdgcn_mfma_f32_16x16x32_bf16((a), (b), (c), 0, 0, 0)

static __device__ __forceinline__ unsigned short f2bf(float f) {
  unsigned u = __builtin_bit_cast(unsigned, f);
  u += 0x7fffu + ((u >> 16) & 1u);  // RNE
  return (unsigned short)(u >> 16);
}

static __device__ __forceinline__ void gload_lds16(const void* g, void* l) {
  __builtin_amdgcn_global_load_lds((__attribute__((address_space(1))) void*)g,
                                   (__attribute__((address_space(3))) void*)l, 16, 0, 0);
}

// ---------------- fp32 -> bf16 conversion ----------------
__global__ __launch_bounds__(256) void cvt_kernel(
    const float* __restrict__ s0, const float* __restrict__ s1,
    const float* __restrict__ s2, const float* __restrict__ s3,
    unsigned short* __restrict__ d0, unsigned short* __restrict__ d1,
    unsigned short* __restrict__ d2, unsigned short* __restrict__ d3, int n) {
  const float* s;
  unsigned short* d;
  switch (blockIdx.y) {
    case 0: s = s0; d = d0; break;
    case 1: s = s1; d = d1; break;
    case 2: s = s2; d = d2; break;
    default: s = s3; d = d3; break;
  }
  int i = (blockIdx.x * 256 + threadIdx.x) * 4;
  if (i >= n) return;
  float4 v = *(const float4*)(s + i);
  ushort4 o;
  o.x = f2bf(v.x); o.y = f2bf(v.y); o.z = f2bf(v.z); o.w = f2bf(v.w);
  *(ushort4*)(d + i) = o;
}

// ---------------- mask -> bitmask ----------------
__global__ __launch_bounds__(256) void maskbits_kernel(const int* __restrict__ mask,
                                                       unsigned* __restrict__ bits) {
  int i = blockIdx.x * 256 + threadIdx.x;
  const int* mp = mask + (size_t)i * 32;
  unsigned wv = 0;
#pragma unroll
  for (int j = 0; j < 8; ++j) {
    int4 m4 = *(const int4*)(mp + j * 4);
    wv |= (m4.x ? 1u : 0u) << (j * 4 + 0);
    wv |= (m4.y ? 1u : 0u) << (j * 4 + 1);
    wv |= (m4.z ? 1u : 0u) << (j * 4 + 2);
    wv |= (m4.w ? 1u : 0u) << (j * 4 + 3);
  }
  bits[i] = wv;
}

// ---------------- shared GEMM body: C = A[M,K] * Bt[N,K]^T, BN=128 ----------------
// mode 0: bf16 [M,N] out. mode 1: bf16 Vt[b][h][d][s]. mode 2: fp32 [M,N].
template <int BM>
static __device__ __forceinline__ void gemm_body(
    const unsigned short* __restrict__ A, const unsigned short* __restrict__ Bt,
    const float* __restrict__ bias, void* __restrict__ Cout, int N, int K,
    float oscale, int mode, unsigned short* lA, unsigned short* lB, int bx, int by) {
  constexpr int MI = BM / 32;
  const int tid = threadIdx.x;
  const int lane = tid & 63;
  const int w = tid >> 6;
  const int wm = w >> 1, wn = w & 1;
  const int lr = lane & 15, lg = lane >> 4;
  const size_t K2 = (size_t)K * 2;

  const char* Ab = (const char*)A + (size_t)bx * BM * K2;
  const char* Bb = (const char*)Bt + (size_t)by * 128 * K2;

  constexpr int NA = BM / 64;  // 4KB chunks for A
  const char* asrc[NA];
  unsigned short* adst[NA];
#pragma unroll
  for (int i = 0; i < NA; ++i) {
    const int o = (tid + i * 256) * 16;
    asrc[i] = Ab + (size_t)(o >> 6) * K2 + (o & 63);
    adst[i] = (unsigned short*)((char*)lA + o);
  }
  const char* bsrc[2];
  unsigned short* bdst[2];
#pragma unroll
  for (int i = 0; i < 2; ++i) {
    const int o = (tid + i * 256) * 16;
    bsrc[i] = Bb + (size_t)(o >> 6) * K2 + (o & 63);
    bdst[i] = (unsigned short*)((char*)lB + o);
  }

  f32x4 acc[MI][4];
  const f32x4 z = {0.f, 0.f, 0.f, 0.f};
#pragma unroll
  for (int mi = 0; mi < MI; ++mi)
#pragma unroll
    for (int ni = 0; ni < 4; ++ni) acc[mi][ni] = z;

  for (int kt = 0; kt < K; kt += 32) {
    __syncthreads();
#pragma unroll
    for (int i = 0; i < NA; ++i) gload_lds16(asrc[i] + kt * 2, adst[i]);
#pragma unroll
    for (int i = 0; i < 2; ++i) gload_lds16(bsrc[i] + kt * 2, bdst[i]);
    __syncthreads();
    s16x8 af[MI], bfr[4];
#pragma unroll
    for (int mi = 0; mi < MI; ++mi)
      af[mi] = *(const s16x8*)(&lA[(wm * (BM / 2) + mi * 16 + lr) * 32 + lg * 8]);
#pragma unroll
    for (int ni = 0; ni < 4; ++ni)
      bfr[ni] = *(const s16x8*)(&lB[(wn * 64 + ni * 16 + lr) * 32 + lg * 8]);
#pragma unroll
    for (int mi = 0; mi < MI; ++mi)
#pragma unroll
      for (int ni = 0; ni < 4; ++ni) acc[mi][ni] = MFMA(af[mi], bfr[ni], acc[mi][ni]);
  }

#pragma unroll
  for (int mi = 0; mi < MI; ++mi) {
    const int row0 = bx * BM + wm * (BM / 2) + mi * 16 + lg * 4;
#pragma unroll
    for (int ni = 0; ni < 4; ++ni) {
      const int col = by * 128 + wn * 64 + ni * 16 + lr;
      const float bv = bias[col];
#pragma unroll
      for (int r = 0; r < 4; ++r) {
        const int row = row0 + r;
        const float val = (acc[mi][ni][r] + bv) * oscale;
        if (mode == 0) {
          ((unsigned short*)Cout)[(size_t)row * N + col] = f2bf(val);
        } else if (mode == 1) {
          const int bb = row >> 11, ss = row & 2047;
          const int hh = col >> 6, dd = col & 63;
          ((unsigned short*)Cout)[(((size_t)((bb * NHEAD + hh) * HDIM + dd)) << 11) + ss] =
              f2bf(val);
        } else {
          ((float*)Cout)[(size_t)row * N + col] = val;
        }
      }
    }
  }
}

// fused Q/K/V projections: grid (32, 8, 3)
__global__ __launch_bounds__(256, 2) void gemm_qkv(
    const unsigned short* __restrict__ qb, const unsigned short* __restrict__ kb,
    const unsigned short* __restrict__ vb, const unsigned short* __restrict__ Wqb,
    const unsigned short* __restrict__ Wkb, const unsigned short* __restrict__ Wvb,
    const float* __restrict__ bq, const float* __restrict__ bk,
    const float* __restrict__ bv, unsigned short* __restrict__ Qp,
    unsigned short* __restrict__ Kp, unsigned short* __restrict__ Vt) {
  __shared__ unsigned short lA[128 * 32];
  __shared__ unsigned short lB[128 * 32];
  const unsigned short *A, *Bt;
  const float* bias;
  void* out;
  int mode;
  float sc;
  switch (blockIdx.z) {
    case 0: A = qb; Bt = Wqb; bias = bq; out = Qp; mode = 0; sc = 0.125f; break;
    case 1: A = kb; Bt = Wkb; bias = bk; out = Kp; mode = 0; sc = 1.f; break;
    default: A = vb; Bt = Wvb; bias = bv; out = Vt; mode = 1; sc = 1.f; break;
  }
  gemm_body<128>(A, Bt, bias, out, 1024, 1024, sc, mode, lA, lB, blockIdx.x, blockIdx.y);
}

// O-projection: BM=64, grid (64, 8)
__global__ __launch_bounds__(256, 2) void gemm_o(
    const unsigned short* __restrict__ A, const unsigned short* __restrict__ Bt,
    const float* __restrict__ bias, float* __restrict__ X) {
  __shared__ unsigned short lA[64 * 32];
  __shared__ unsigned short lB[128 * 32];
  gemm_body<64>(A, Bt, bias, X, 1024, 1024, 1.f, 2, lA, lB, blockIdx.x, blockIdx.y);
}

// ---------------- fused attention v2 ----------------
// grid (S/64, B*H), 256 threads (4 waves, 16 q-rows/wave). Swapped QK^T:
// mfma(K,Q) -> lane lr owns q-row, regs hold 4 consecutive k cols. No-max softmax.
__global__ __launch_bounds__(256, 4) void attn_kernel(
    const unsigned short* __restrict__ Qp,  // [B*S, HID] bf16, pre-scaled by 1/8
    const unsigned short* __restrict__ Kp,  // [B*S, HID] bf16
    const unsigned short* __restrict__ Vt,  // [B*H*HDIM, S] bf16
    const unsigned* __restrict__ Mw,        // [B, S, 64] bitmask
    unsigned short* __restrict__ AV,        // [B*S, HID] bf16
    float* __restrict__ Pout) {             // [B*H*S, S] fp32
  __shared__ unsigned short P_lds[4][16][72];
  const int tid = threadIdx.x;
  const int lane = tid & 63;
  const int w = tid >> 6;
  const int lr = lane & 15;
  const int lg = lane >> 4;
  const int bh = blockIdx.y;
  const int b = bh >> 4;
  const int h = bh & 15;
  const int qw = blockIdx.x * 64 + w * 16;  // wave's first q row

  const unsigned short* Qb = Qp + (size_t)(b * SLEN + qw) * HID + h * HDIM;
  const unsigned short* Kb = Kp + (size_t)(b * SLEN) * HID + h * HDIM;
  const unsigned short* Vb = Vt + (size_t)bh * HDIM * SLEN;
  const unsigned* Mrow = Mw + (size_t)(b * SLEN + qw + lr) * 64;
  float* Prow = Pout + ((size_t)bh * SLEN + qw + lr) * SLEN;

  const s16x8 qf0 = *(const s16x8*)(Qb + (size_t)lr * HID + lg * 8);
  const s16x8 qf1 = *(const s16x8*)(Qb + (size_t)lr * HID + 32 + lg * 8);
  const f32x4 z = {0.f, 0.f, 0.f, 0.f};

  // ---- pass 1: row sums ----
  float rs = 0.f;
  for (int c0 = 0; c0 < SLEN; c0 += 64) {
    const uint2 mw2 = *(const uint2*)(Mrow + (c0 >> 5));
    f32x4 acc[4];
#pragma unroll
    for (int t = 0; t < 4; ++t) {
      const unsigned short* kr = Kb + (size_t)(c0 + t * 16 + lr) * HID;
      const s16x8 k0 = *(const s16x8*)(kr + lg * 8);
      const s16x8 k1 = *(const s16x8*)(kr + 32 + lg * 8);
      acc[t] = MFMA(k0, qf0, z);
      acc[t] = MFMA(k1, qf1, acc[t]);
    }
#pragma unroll
    for (int t = 0; t < 4; ++t) {
      const unsigned word = (t < 2) ? mw2.x : mw2.y;
      const unsigned bits = word >> ((t & 1) * 16 + lg * 4);
#pragma unroll
      for (int r = 0; r < 4; ++r) {
        const float p = ((bits >> r) & 1u) ? __expf(acc[t][r]) : 0.f;
        rs += p;
      }
    }
  }
  rs += __shfl_xor(rs, 16);
  rs += __shfl_xor(rs, 32);
  const float rinv = 1.f / rs;

  // ---- pass 2: recompute, write P, accumulate PV ----
  f32x4 oacc[4];
#pragma unroll
  for (int d0 = 0; d0 < 4; ++d0) oacc[d0] = z;

  for (int c0 = 0; c0 < SLEN; c0 += 64) {
    const uint2 mw2 = *(const uint2*)(Mrow + (c0 >> 5));
    f32x4 acc[4];
#pragma unroll
    for (int t = 0; t < 4; ++t) {
      const unsigned short* kr = Kb + (size_t)(c0 + t * 16 + lr) * HID;
      const s16x8 k0 = *(const s16x8*)(kr + lg * 8);
      const s16x8 k1 = *(const s16x8*)(kr + 32 + lg * 8);
      acc[t] = MFMA(k0, qf0, z);
      acc[t] = MFMA(k1, qf1, acc[t]);
    }
#pragma unroll
    for (int t = 0; t < 4; ++t) {
      const unsigned word = (t < 2) ? mw2.x : mw2.y;
      const unsigned bits = word >> ((t & 1) * 16 + lg * 4);
      f32x4 pv;
#pragma unroll
      for (int r = 0; r < 4; ++r)
        pv[r] = ((bits >> r) & 1u) ? __expf(acc[t][r]) * rinv : 0.f;
      *(f32x4*)(Prow + c0 + t * 16 + lg * 4) = pv;
      const unsigned lo = (unsigned)f2bf(pv[0]) | ((unsigned)f2bf(pv[1]) << 16);
      const unsigned hi = (unsigned)f2bf(pv[2]) | ((unsigned)f2bf(pv[3]) << 16);
      *(uint2*)(&P_lds[w][lr][t * 16 + lg * 4]) = make_uint2(lo, hi);
    }
    const s16x8 pf0 = *(const s16x8*)(&P_lds[w][lr][lg * 8]);
    const s16x8 pf1 = *(const s16x8*)(&P_lds[w][lr][32 + lg * 8]);
#pragma unroll
    for (int d0 = 0; d0 < 4; ++d0) {
      const unsigned short* vr = Vb + (size_t)(d0 * 16 + lr) * SLEN + c0;
      const s16x8 v0 = *(const s16x8*)(vr + lg * 8);
      const s16x8 v1 = *(const s16x8*)(vr + 32 + lg * 8);
      oacc[d0] = MFMA(pf0, v0, oacc[d0]);
      oacc[d0] = MFMA(pf1, v1, oacc[d0]);
    }
  }

#pragma unroll
  for (int d0 = 0; d0 < 4; ++d0)
#pragma unroll
    for (int r = 0; r < 4; ++r) {
      const int qrow = qw + lg * 4 + r;
      AV[(size_t)(b * SLEN + qrow) * HID + h * HDIM + d0 * 16 + lr] = f2bf(oacc[d0][r]);
    }
}

extern "C" void kernel_launch(void* const* d_in, const int* in_sizes, int n_in,
                              void* d_out, int out_size, void* d_ws, size_t ws_size,
                              hipStream_t stream) {
  const float* q = (const float*)d_in[0];
  const float* k = (const float*)d_in[1];
  const float* v = (const float*)d_in[2];
  const int* mask = (const int*)d_in[3];
  const float* Wq = (const float*)d_in[4];
  const float* bq = (const float*)d_in[5];
  const float* Wk = (const float*)d_in[6];
  const float* bk = (const float*)d_in[7];
  const float* Wv = (const float*)d_in[8];
  const float* bv = (const float*)d_in[9];
  const float* Wo = (const float*)d_in[10];
  const float* bo = (const float*)d_in[11];

  unsigned short* qb = (unsigned short*)d_ws;
  unsigned short* kb = qb + 4194304;
  unsigned short* vb = kb + 4194304;
  unsigned short* Wqb = vb + 4194304;
  unsigned short* Wkb = Wqb + 1048576;
  unsigned short* Wvb = Wkb + 1048576;
  unsigned short* Wob = Wvb + 1048576;
  unsigned short* Qp = Wob + 1048576;
  unsigned short* Kp = Qp + 4194304;
  unsigned short* Vt = Kp + 4194304;
  unsigned short* AVb = Vt + 4194304;
  unsigned* Mw = (unsigned*)(AVb + 4194304);

  float* X = (float*)d_out;
  float* Pout = X + 4194304;

  cvt_kernel<<<dim3(4096, 3), 256, 0, stream>>>(q, k, v, v, qb, kb, vb, vb, 4194304);
  cvt_kernel<<<dim3(1024, 4), 256, 0, stream>>>(Wq, Wk, Wv, Wo, Wqb, Wkb, Wvb, Wob, 1048576);
  maskbits_kernel<<<1024, 256, 0, stream>>>(mask, Mw);
  gemm_qkv<<<dim3(32, 8, 3), 256, 0, stream>>>(qb, kb, vb, Wqb, Wkb, Wvb, bq, bk, bv, Qp, Kp, Vt);
  attn_kernel<<<dim3(32, 32), 256, 0, stream>>>(Qp, Kp, Vt, Mw, AVb, Pout);
  gemm_o<<<dim3(64, 8), 256, 0, stream>>>(AVb, Wob, bo, X);
}